// Round 10
// baseline (1306.717 us; speedup 1.0000x reference)
//
#include <hip/hip_runtime.h>

// GCN layer: out = relu(segment_sum(edge_val * (x@W + b)[edge_col] -> edge_row))
// N=100000 nodes, E=1600000 edges, 256 -> 128 features, fp32 in/out.
//
// Round 16: REVERT r15 co-launch (gcn_k3 80us @ 9.7% occupancy: heterogeneous
// merge = max(VGPR,LDS) of both halves kills the latency-bound half). Two
// structural cuts on the r14 baseline instead:
//  1) bhist folded into gemm as a SEQUENTIAL per-block prologue (each of the
//     1250 gemm blocks histograms its 1280-edge slice into LDS then flushes
//     once) -- same-kernel phase fusion has no resource-max penalty. The
//     ~40us standalone bhist dispatch disappears.
//  2) place + row_start DELETED. Aggregate becomes per-bucket LDS
//     scatter-accumulate (gcn_aggscat): 1 block per bucket (1021), 50KB LDS
//     acc[98][132] (pad-132 -> per-row bank shift 4), 16 lanes/edge ush8
//     gather, ds_add_f32 accumulate, ReLU writeback. Removes place's
//     dispatch and packed's 12.8MB rewrite+reread; within-bucket ordering
//     is no longer needed.
// Pipeline: memset -> gemm+hist -> bscan -> bin -> aggscat.
// gemm core (r9), bin (r14) unchanged.

constexpr int kNodes = 100000;
constexpr int kEdges = 1600000;
constexpr int kInF   = 256;
constexpr int kOutF  = 128;
constexpr int kTiles = kNodes / 16;                 // 6250
constexpr int kGemmBlocks = 1250;                   // 5 tiles per block
constexpr int kEPG = kEdges / kGemmBlocks;          // 1280 edges per gemm block

constexpr int kNB  = 1024;                          // buckets
constexpr int kRB  = 98;                            // rows/bucket (1024*98 >= N)
constexpr int kNBu = (kNodes + kRB - 1) / kRB;      // 1021 used buckets
constexpr int kBinBlocks = 256;
constexpr int kEPB = kEdges / kBinBlocks;           // 6250 edges/block

typedef __attribute__((ext_vector_type(8))) short short8;
typedef __attribute__((ext_vector_type(8))) unsigned short ush8;
typedef __attribute__((ext_vector_type(4))) float floatx4;

__device__ inline unsigned short f2bf_rne(float f) {
    unsigned int u = __float_as_uint(f);
    unsigned int r = u + 0x7FFFu + ((u >> 16) & 1u);
    return (unsigned short)(r >> 16);
}
__device__ inline float bf2f(unsigned short h) {
    return __uint_as_float(((unsigned int)h) << 16);
}

// 8 fp32 -> 8 bf16 (RNE) via 4x v_cvt_pk_bf16_f32.
__device__ inline short8 cvt8_bf16(const float4 a, const float4 b) {
    union { short8 s; unsigned int u[4]; } r;
    asm("v_cvt_pk_bf16_f32 %0, %1, %2" : "=v"(r.u[0]) : "v"(a.x), "v"(a.y));
    asm("v_cvt_pk_bf16_f32 %0, %1, %2" : "=v"(r.u[1]) : "v"(a.z), "v"(a.w));
    asm("v_cvt_pk_bf16_f32 %0, %1, %2" : "=v"(r.u[2]) : "v"(b.x), "v"(b.y));
    asm("v_cvt_pk_bf16_f32 %0, %1, %2" : "=v"(r.u[3]) : "v"(b.z), "v"(b.w));
    return r.s;
}

// async 16B global->LDS (dest = wave-uniform base + lane*16)
__device__ inline void gload_lds16(const void* g, void* l) {
    __builtin_amdgcn_global_load_lds(
        (const __attribute__((address_space(1))) unsigned int*)g,
        (__attribute__((address_space(3))) unsigned int*)l,
        16, 0, 0);
}

// ---------------------------------------------------------------------------
// GEMM + edge histogram. Phase 0 (per block, sequential): LDS hist of the
// block's 1280-edge slice over 1024 buckets, one flush atomic per nonzero
// bucket. Phase 1: r9 gemm core (global_load_lds dbuf + XOR swizzle).
// LDS: 32KB dbuf + 4KB cnt = 36.8KB -> 4 blocks/CU.
// ---------------------------------------------------------------------------
__global__ __launch_bounds__(256) void gcn_gemm(const float* __restrict__ x,
                                                const float* __restrict__ W,
                                                const float* __restrict__ b,
                                                unsigned short* __restrict__ support,
                                                const int* __restrict__ erow,
                                                int* __restrict__ bucket_tot) {
    __shared__ __align__(16) float lbuf[2][4096];   // 32,768 B
    __shared__ int cnt[kNB];                        //  4,096 B

    const int tid  = threadIdx.x;
    const int lane = tid & 63;
    const int wv   = tid >> 6;
    const int rowl = lane & 15;
    const int quad = lane >> 4;
    const int colbase = wv * 32;

    // ---- phase 0: histogram this block's edge slice ----
    for (int i = tid; i < kNB; i += 256) cnt[i] = 0;
    __syncthreads();
    {
        const int eb0 = blockIdx.x * kEPG;
        const int eb1 = min(eb0 + kEPG, kEdges);
        for (int e = eb0 + tid; e < eb1; e += 256)
            atomicAdd(&cnt[(unsigned int)erow[e] / (unsigned int)kRB], 1);
    }
    __syncthreads();
    for (int i = tid; i < kNB; i += 256) {
        const int c = cnt[i];
        if (c) atomicAdd(&bucket_tot[i], c);
    }

    // ---- phase 1: gemm (r9 core) ----
    short8 bfrag[2][8];
#pragma unroll
    for (int ct = 0; ct < 2; ++ct) {
        const int col = colbase + ct * 16 + rowl;
#pragma unroll
        for (int kc = 0; kc < 8; ++kc) {
            const int kb = kc * 32 + quad * 8;
            short8 f;
#pragma unroll
            for (int j = 0; j < 8; ++j)
                f[j] = (short)f2bf_rne(W[(size_t)(kb + j) * kOutF + col]);
            bfrag[ct][kc] = f;
        }
    }
    const float bias0 = b[colbase + rowl];
    const float bias1 = b[colbase + 16 + rowl];

    const int G = gridDim.x;
    int t = blockIdx.x;

#define GEMM_STAGE(buf_, tile_)                                                   \
    do {                                                                          \
        const float* tb_ = x + (size_t)(tile_) * 16 * kInF;                       \
        _Pragma("unroll")                                                         \
        for (int i_ = 0; i_ < 4; ++i_) {                                          \
            const int row_ = i_ * 4 + wv;                                         \
            gload_lds16(tb_ + (size_t)row_ * kInF + ((lane ^ (row_ & 7)) << 2),   \
                        &lbuf[buf_][row_ << 8]);                                  \
        }                                                                         \
    } while (0)

    if (t < kTiles) GEMM_STAGE(0, t);
    int cur = 0;

    for (; t < kTiles; t += G) {
        const int tn = t + G;
        asm volatile("s_waitcnt vmcnt(0)" ::: "memory");
        __syncthreads();
        if (tn < kTiles) GEMM_STAGE(cur ^ 1, tn);

        const int r0 = t * 16;
        const float* base = &lbuf[cur][rowl << 8];
        const int rsw = rowl & 7;
        floatx4 acc0 = {0.f, 0.f, 0.f, 0.f};
        floatx4 acc1 = {0.f, 0.f, 0.f, 0.f};
#pragma unroll
        for (int kc = 0; kc < 8; ++kc) {
            const int g0 = (kc << 3) + (quad << 1);
            const float4 v0 = *reinterpret_cast<const float4*>(base + ((g0 ^ rsw) << 2));
            const float4 v1 = *reinterpret_cast<const float4*>(base + (((g0 + 1) ^ rsw) << 2));
            const short8 a = cvt8_bf16(v0, v1);
            acc0 = __builtin_amdgcn_mfma_f32_16x16x32_bf16(a, bfrag[0][kc], acc0, 0, 0, 0);
            acc1 = __builtin_amdgcn_mfma_f32_16x16x32_bf16(a, bfrag[1][kc], acc1, 0, 0, 0);
        }
#pragma unroll
        for (int reg = 0; reg < 4; ++reg) {
            const size_t rbase = (size_t)(r0 + quad * 4 + reg) * kOutF + colbase;
            support[rbase + rowl]      = f2bf_rne(acc0[reg] + bias0);
            support[rbase + 16 + rowl] = f2bf_rne(acc1[reg] + bias1);
        }
        cur ^= 1;
    }
#undef GEMM_STAGE
}

// ---------------------------------------------------------------------------
// Bucket scan: one block, 1024-wide exclusive scan (4 elems/thread).
// ---------------------------------------------------------------------------
__global__ __launch_bounds__(256) void gcn_bscan(const int* __restrict__ bucket_tot,
                                                 int* __restrict__ bucket_base,
                                                 int* __restrict__ cursor) {
    __shared__ int s[kNB];
    const int tid = threadIdx.x;
    int t[4];
#pragma unroll
    for (int j = 0; j < 4; ++j) {
        const int idx = tid + j * 256;
        t[j] = bucket_tot[idx];
        s[idx] = t[j];
    }
    __syncthreads();
    for (int off = 1; off < kNB; off <<= 1) {
        int v[4];
#pragma unroll
        for (int j = 0; j < 4; ++j) {
            const int idx = tid + j * 256;
            v[j] = (idx >= off) ? s[idx - off] : 0;
        }
        __syncthreads();
#pragma unroll
        for (int j = 0; j < 4; ++j) s[tid + j * 256] += v[j];
        __syncthreads();
    }
#pragma unroll
    for (int j = 0; j < 4; ++j) {
        const int idx = tid + j * 256;
        const int excl = s[idx] - t[j];
        bucket_base[idx] = excl;
        cursor[idx]      = excl;
    }
    if (tid == 255) bucket_base[kNB] = kEdges;
}

// ---------------------------------------------------------------------------
// Bin (r14, unchanged): scatter edges into bucket runs (write-combined,
// ~6-edge runs). packed.x = (row_local<<17)|col, packed.y = val.
// ---------------------------------------------------------------------------
__global__ __launch_bounds__(256) void gcn_bin(const int* __restrict__ erow,
                                               const int* __restrict__ ecol,
                                               const float* __restrict__ eval,
                                               int* __restrict__ cursor,
                                               int2* __restrict__ packed) {
    __shared__ int cnt[kNB];   // counts -> absolute run base after flush
    __shared__ int rk[kNB];    // run rank
    const int tid = threadIdx.x;
    const int eb0 = blockIdx.x * kEPB;
    const int eb1 = min(eb0 + kEPB, kEdges);
    for (int i = tid; i < kNB; i += 256) { cnt[i] = 0; rk[i] = 0; }
    __syncthreads();
#pragma unroll 4
    for (int e = eb0 + tid; e < eb1; e += 256)
        atomicAdd(&cnt[(unsigned int)erow[e] / (unsigned int)kRB], 1);
    __syncthreads();
    for (int i = tid; i < kNB; i += 256) {
        const int c = cnt[i];
        cnt[i] = c ? atomicAdd(&cursor[i], c) : 0;
    }
    __syncthreads();
#pragma unroll 4
    for (int e = eb0 + tid; e < eb1; e += 256) {
        const int r = erow[e];
        const unsigned int bk = (unsigned int)r / (unsigned int)kRB;
        const int rl = r - (int)bk * kRB;
        const int pos = cnt[bk] + atomicAdd(&rk[bk], 1);
        packed[pos] = make_int2((rl << 17) | ecol[e], __float_as_int(eval[e]));
    }
}

// ---------------------------------------------------------------------------
// Aggregate via per-bucket LDS scatter-accumulate + ReLU. One block per
// bucket: zero acc[98][132] (pad-132 -> per-row bank shift of 4), stream the
// bucket's packed segment in 256-record LDS chunks, 16 lanes/edge gather
// ush8 from support, ds_add_f32 into acc, then ReLU writeback (coalesced
// float4). No within-bucket ordering or row_start needed.
// ---------------------------------------------------------------------------
__global__ __launch_bounds__(256) void gcn_aggscat(const int* __restrict__ bucket_base,
                                                   const int2* __restrict__ packed,
                                                   const unsigned short* __restrict__ support,
                                                   float* __restrict__ out) {
    __shared__ float acc[kRB][132];   // 51,744 B
    __shared__ int2  stg[256];        //  2,048 B
    const int bk = blockIdx.x;
    const int r0 = bk * kRB;
    const int NR = min(kRB, kNodes - r0);
    const int tid = threadIdx.x;
    const int grp = tid >> 4;         // 16 edge-groups per block
    const int gl  = tid & 15;         // 8 features per lane

    for (int i = tid; i < kRB * 132; i += 256)
        (&acc[0][0])[i] = 0.f;

    const int bb = bucket_base[bk];
    const int be = bucket_base[bk + 1];
    const unsigned short* sb = support + gl * 8;

    for (int base = bb; base < be; base += 256) {
        const int m = min(256, be - base);
        __syncthreads();              // previous chunk fully consumed (also covers zero-init)
        if (tid < m) stg[tid] = packed[base + tid];
        __syncthreads();
#pragma unroll 4
        for (int it = 0; it < 16; ++it) {
            const int ei = it * 16 + grp;
            if (ei < m) {
                const int2 p = stg[ei];
                const int rl = p.x >> 17;
                const float v = __int_as_float(p.y);
                const ush8 g = *reinterpret_cast<const ush8*>(
                    sb + (size_t)(p.x & 0x1FFFF) * kOutF);
                float* a = &acc[rl][gl * 8];
#pragma unroll
                for (int j = 0; j < 8; ++j)
                    atomicAdd(&a[j], v * bf2f(g[j]));
            }
        }
    }
    __syncthreads();                  // all accumulates done

    for (int idx = tid; idx < NR * 32; idx += 256) {
        const int r = idx >> 5;
        const int c = (idx & 31) * 4;
        const float4 a4 = *reinterpret_cast<const float4*>(&acc[r][c]);
        const float4 o = make_float4(fmaxf(a4.x, 0.f), fmaxf(a4.y, 0.f),
                                     fmaxf(a4.z, 0.f), fmaxf(a4.w, 0.f));
        *reinterpret_cast<float4*>(out + (size_t)(r0 + r) * kOutF + c) = o;
    }
}

extern "C" void kernel_launch(void* const* d_in, const int* in_sizes, int n_in,
                              void* d_out, int out_size, void* d_ws, size_t ws_size,
                              hipStream_t stream) {
    const float* x    = (const float*)d_in[0];
    const int*   erow = (const int*)  d_in[1];
    const int*   ecol = (const int*)  d_in[2];
    const float* eval = (const float*)d_in[3];
    const float* W    = (const float*)d_in[4];
    const float* b    = (const float*)d_in[5];
    float* out = (float*)d_out;

    char* ws = (char*)d_ws;
    unsigned short* support = (unsigned short*)(ws);       // 25,600,000 B (row-major [N][128])
    int2* packed      = (int2*)(ws + 25600000);            // 12,800,000 B
    int*  bucket_tot  = (int*) (ws + 38400000);            //      4,096 B
    int*  bucket_base = (int*) (ws + 38404096);            //      4,100 B
    int*  cursor      = (int*) (ws + 38408200);            //      4,096 B

    hipMemsetAsync(bucket_tot, 0, kNB * sizeof(int), stream);

    // 1) support = bf16(x@W + b); each block also histograms its edge slice
    gcn_gemm<<<kGemmBlocks, 256, 0, stream>>>(x, W, b, support, erow, bucket_tot);

    // 2) bucket scan -> bases/cursors; 3) bin edges into bucket segments
    gcn_bscan<<<1, 256, 0, stream>>>(bucket_tot, bucket_base, cursor);
    gcn_bin  <<<kBinBlocks, 256, 0, stream>>>(erow, ecol, eval, cursor, packed);

    // 4) per-bucket scatter-accumulate aggregate + relu
    gcn_aggscat<<<kNBu, 256, 0, stream>>>(bucket_base, packed, support, out);
}

// Round 11
// 342.891 us; speedup vs baseline: 3.8109x; 3.8109x over previous
//
#include <hip/hip_runtime.h>

// GCN layer: out = relu(segment_sum(edge_val * (x@W + b)[edge_col] -> edge_row))
// N=100000 nodes, E=1600000 edges, 256 -> 128 features, fp32 in/out.
//
// Round 17: REVERT r16's aggscat (1066us: 205M LDS float atomicAdds are
// CAS-class + same-row collisions -> total serialization; model was off
// 60x). Restore the proven place + ordered-aggregate pair (r12/r14,
// 64.5us). KEEP r16's one sound piece: bhist folded into gemm as a
// sequential per-block prologue (no resource-max penalty; deletes the
// standalone ~30-40us bhist dispatch; flush atomics overlap gemm's
// W-fragment prologue).
// Pipeline: memset -> gemm+hist -> bscan -> bin -> place -> aggregate.
// All bodies identical to their last proven versions (r9 gemm core, r14
// CSR params kNB=1024/kRB=98/kCap=1792, r12 aggregate).

constexpr int kNodes = 100000;
constexpr int kEdges = 1600000;
constexpr int kInF   = 256;
constexpr int kOutF  = 128;
constexpr int kTiles = kNodes / 16;                 // 6250
constexpr int kGemmBlocks = 1250;                   // 5 tiles per block
constexpr int kEPG = kEdges / kGemmBlocks;          // 1280 edges per gemm block

constexpr int kNB  = 1024;                          // buckets
constexpr int kRB  = 98;                            // rows/bucket (1024*98 >= N)
constexpr int kCap = 1792;                          // LDS-staged edges/bucket
constexpr int kBinBlocks = 256;
constexpr int kEPB = kEdges / kBinBlocks;           // 6250 edges/block

constexpr int kTileCap = 1024;                      // staged edges per 16-node agg tile

typedef __attribute__((ext_vector_type(8))) short short8;
typedef __attribute__((ext_vector_type(8))) unsigned short ush8;
typedef __attribute__((ext_vector_type(4))) float floatx4;

__device__ inline unsigned short f2bf_rne(float f) {
    unsigned int u = __float_as_uint(f);
    unsigned int r = u + 0x7FFFu + ((u >> 16) & 1u);
    return (unsigned short)(r >> 16);
}
__device__ inline float bf2f(unsigned short h) {
    return __uint_as_float(((unsigned int)h) << 16);
}

// 8 fp32 -> 8 bf16 (RNE) via 4x v_cvt_pk_bf16_f32.
__device__ inline short8 cvt8_bf16(const float4 a, const float4 b) {
    union { short8 s; unsigned int u[4]; } r;
    asm("v_cvt_pk_bf16_f32 %0, %1, %2" : "=v"(r.u[0]) : "v"(a.x), "v"(a.y));
    asm("v_cvt_pk_bf16_f32 %0, %1, %2" : "=v"(r.u[1]) : "v"(a.z), "v"(a.w));
    asm("v_cvt_pk_bf16_f32 %0, %1, %2" : "=v"(r.u[2]) : "v"(b.x), "v"(b.y));
    asm("v_cvt_pk_bf16_f32 %0, %1, %2" : "=v"(r.u[3]) : "v"(b.z), "v"(b.w));
    return r.s;
}

// async 16B global->LDS (dest = wave-uniform base + lane*16)
__device__ inline void gload_lds16(const void* g, void* l) {
    __builtin_amdgcn_global_load_lds(
        (const __attribute__((address_space(1))) unsigned int*)g,
        (__attribute__((address_space(3))) unsigned int*)l,
        16, 0, 0);
}

// ---------------------------------------------------------------------------
// GEMM + edge histogram (r16 fusion, r9 gemm core).
// Phase 0 (sequential): LDS hist of the block's 1280-edge slice, one flush
// atomic per nonzero bucket. Phase 1: gemm (global_load_lds dbuf + swizzle).
// LDS: 32KB dbuf + 4KB cnt = 36.8KB -> 4 blocks/CU.
// ---------------------------------------------------------------------------
__global__ __launch_bounds__(256) void gcn_gemm(const float* __restrict__ x,
                                                const float* __restrict__ W,
                                                const float* __restrict__ b,
                                                unsigned short* __restrict__ support,
                                                const int* __restrict__ erow,
                                                int* __restrict__ bucket_tot) {
    __shared__ __align__(16) float lbuf[2][4096];   // 32,768 B
    __shared__ int cnt[kNB];                        //  4,096 B

    const int tid  = threadIdx.x;
    const int lane = tid & 63;
    const int wv   = tid >> 6;
    const int rowl = lane & 15;
    const int quad = lane >> 4;
    const int colbase = wv * 32;

    // ---- phase 0: histogram this block's edge slice ----
    for (int i = tid; i < kNB; i += 256) cnt[i] = 0;
    __syncthreads();
    {
        const int eb0 = blockIdx.x * kEPG;
        const int eb1 = min(eb0 + kEPG, kEdges);
        for (int e = eb0 + tid; e < eb1; e += 256)
            atomicAdd(&cnt[(unsigned int)erow[e] / (unsigned int)kRB], 1);
    }
    __syncthreads();
    for (int i = tid; i < kNB; i += 256) {
        const int c = cnt[i];
        if (c) atomicAdd(&bucket_tot[i], c);
    }

    // ---- phase 1: gemm (r9 core) ----
    short8 bfrag[2][8];
#pragma unroll
    for (int ct = 0; ct < 2; ++ct) {
        const int col = colbase + ct * 16 + rowl;
#pragma unroll
        for (int kc = 0; kc < 8; ++kc) {
            const int kb = kc * 32 + quad * 8;
            short8 f;
#pragma unroll
            for (int j = 0; j < 8; ++j)
                f[j] = (short)f2bf_rne(W[(size_t)(kb + j) * kOutF + col]);
            bfrag[ct][kc] = f;
        }
    }
    const float bias0 = b[colbase + rowl];
    const float bias1 = b[colbase + 16 + rowl];

    const int G = gridDim.x;
    int t = blockIdx.x;

#define GEMM_STAGE(buf_, tile_)                                                   \
    do {                                                                          \
        const float* tb_ = x + (size_t)(tile_) * 16 * kInF;                       \
        _Pragma("unroll")                                                         \
        for (int i_ = 0; i_ < 4; ++i_) {                                          \
            const int row_ = i_ * 4 + wv;                                         \
            gload_lds16(tb_ + (size_t)row_ * kInF + ((lane ^ (row_ & 7)) << 2),   \
                        &lbuf[buf_][row_ << 8]);                                  \
        }                                                                         \
    } while (0)

    if (t < kTiles) GEMM_STAGE(0, t);
    int cur = 0;

    for (; t < kTiles; t += G) {
        const int tn = t + G;
        asm volatile("s_waitcnt vmcnt(0)" ::: "memory");
        __syncthreads();
        if (tn < kTiles) GEMM_STAGE(cur ^ 1, tn);

        const int r0 = t * 16;
        const float* base = &lbuf[cur][rowl << 8];
        const int rsw = rowl & 7;
        floatx4 acc0 = {0.f, 0.f, 0.f, 0.f};
        floatx4 acc1 = {0.f, 0.f, 0.f, 0.f};
#pragma unroll
        for (int kc = 0; kc < 8; ++kc) {
            const int g0 = (kc << 3) + (quad << 1);
            const float4 v0 = *reinterpret_cast<const float4*>(base + ((g0 ^ rsw) << 2));
            const float4 v1 = *reinterpret_cast<const float4*>(base + (((g0 + 1) ^ rsw) << 2));
            const short8 a = cvt8_bf16(v0, v1);
            acc0 = __builtin_amdgcn_mfma_f32_16x16x32_bf16(a, bfrag[0][kc], acc0, 0, 0, 0);
            acc1 = __builtin_amdgcn_mfma_f32_16x16x32_bf16(a, bfrag[1][kc], acc1, 0, 0, 0);
        }
#pragma unroll
        for (int reg = 0; reg < 4; ++reg) {
            const size_t rbase = (size_t)(r0 + quad * 4 + reg) * kOutF + colbase;
            support[rbase + rowl]      = f2bf_rne(acc0[reg] + bias0);
            support[rbase + 16 + rowl] = f2bf_rne(acc1[reg] + bias1);
        }
        cur ^= 1;
    }
#undef GEMM_STAGE
}

// ---------------------------------------------------------------------------
// Bucket scan: one block, 1024-wide exclusive scan (4 elems/thread). (r14)
// ---------------------------------------------------------------------------
__global__ __launch_bounds__(256) void gcn_bscan(const int* __restrict__ bucket_tot,
                                                 int* __restrict__ bucket_base,
                                                 int* __restrict__ cursor,
                                                 int* __restrict__ row_start) {
    __shared__ int s[kNB];
    const int tid = threadIdx.x;
    int t[4];
#pragma unroll
    for (int j = 0; j < 4; ++j) {
        const int idx = tid + j * 256;
        t[j] = bucket_tot[idx];
        s[idx] = t[j];
    }
    __syncthreads();
    for (int off = 1; off < kNB; off <<= 1) {
        int v[4];
#pragma unroll
        for (int j = 0; j < 4; ++j) {
            const int idx = tid + j * 256;
            v[j] = (idx >= off) ? s[idx - off] : 0;
        }
        __syncthreads();
#pragma unroll
        for (int j = 0; j < 4; ++j) s[tid + j * 256] += v[j];
        __syncthreads();
    }
#pragma unroll
    for (int j = 0; j < 4; ++j) {
        const int idx = tid + j * 256;
        const int excl = s[idx] - t[j];
        bucket_base[idx] = excl;
        cursor[idx]      = excl;
    }
    if (tid == 255) {
        bucket_base[kNB]  = kEdges;
        row_start[kNodes] = kEdges;
    }
}

// ---------------------------------------------------------------------------
// Bin (r14, unchanged): scatter edges into bucket runs (write-combined,
// ~6-edge runs). packed.x = (row_local<<17)|col, packed.y = val.
// ---------------------------------------------------------------------------
__global__ __launch_bounds__(256) void gcn_bin(const int* __restrict__ erow,
                                               const int* __restrict__ ecol,
                                               const float* __restrict__ eval,
                                               int* __restrict__ cursor,
                                               int2* __restrict__ packed) {
    __shared__ int cnt[kNB];   // counts -> absolute run base after flush
    __shared__ int rk[kNB];    // run rank
    const int tid = threadIdx.x;
    const int eb0 = blockIdx.x * kEPB;
    const int eb1 = min(eb0 + kEPB, kEdges);
    for (int i = tid; i < kNB; i += 256) { cnt[i] = 0; rk[i] = 0; }
    __syncthreads();
#pragma unroll 4
    for (int e = eb0 + tid; e < eb1; e += 256)
        atomicAdd(&cnt[(unsigned int)erow[e] / (unsigned int)kRB], 1);
    __syncthreads();
    for (int i = tid; i < kNB; i += 256) {
        const int c = cnt[i];
        cnt[i] = c ? atomicAdd(&cursor[i], c) : 0;
    }
    __syncthreads();
#pragma unroll 4
    for (int e = eb0 + tid; e < eb1; e += 256) {
        const int r = erow[e];
        const unsigned int bk = (unsigned int)r / (unsigned int)kRB;
        const int rl = r - (int)bk * kRB;
        const int pos = cnt[bk] + atomicAdd(&rk[bk], 1);
        packed[pos] = make_int2((rl << 17) | ecol[e], __float_as_int(eval[e]));
    }
}

// ---------------------------------------------------------------------------
// Place (r14, unchanged): 1024 blocks (one per bucket), 15.3KB LDS ->
// 4 blocks/CU. Stage bucket in LDS (+reg tail), LDS row hist, 128-wide
// scan, write row_start, scatter via LDS cursors.
// ---------------------------------------------------------------------------
__global__ __launch_bounds__(256) void gcn_place(const int* __restrict__ bucket_base,
                                                 int* __restrict__ row_start,
                                                 int2* __restrict__ packed) {
    __shared__ int2 st[kCap];    // 14,336 B
    __shared__ int  s[128];      //     512 B
    __shared__ int  rcur[kRB];   //     392 B
    const int bk = blockIdx.x;
    const int r0 = bk * kRB;
    if (r0 >= kNodes) return;
    const int r1 = min(r0 + kRB, kNodes);
    const int NR = r1 - r0;
    const int bb = bucket_base[bk];
    const int s1 = bucket_base[bk + 1];
    const int size   = s1 - bb;
    const int staged = min(size, kCap);
    const int tid = threadIdx.x;

    if (tid < 128) s[tid] = 0;
    __syncthreads();

    for (int i = tid; i < staged; i += 256) {
        const int2 p = packed[bb + i];
        st[i] = p;
        atomicAdd(&s[p.x >> 17], 1);
    }
    int2 tail[8];
    int  nt = 0;
    for (int i = kCap + tid; i < size; i += 256) {
        if (nt < 8) {
            tail[nt] = packed[bb + i];
            atomicAdd(&s[tail[nt].x >> 17], 1);
            ++nt;
        }
    }
    __syncthreads();   // all reads + counts done (in-place safe)

    for (int off = 1; off < 128; off <<= 1) {
        int v = 0;
        if (tid < 128 && tid >= off) v = s[tid - off];
        __syncthreads();
        if (tid < 128) s[tid] += v;
        __syncthreads();
    }
    if (tid < NR) {
        const int excl = tid ? s[tid - 1] : 0;
        row_start[r0 + tid] = bb + excl;
        rcur[tid] = excl;
    }
    __syncthreads();

    for (int i = tid; i < staged; i += 256) {
        const int2 p  = st[i];
        const int pos = bb + atomicAdd(&rcur[p.x >> 17], 1);
        packed[pos] = make_int2(p.x & 0x1FFFF, p.y);
    }
#pragma unroll
    for (int t = 0; t < 8; ++t) {
        if (t < nt) {
            const int2 p  = tail[t];
            const int pos = bb + atomicAdd(&rcur[p.x >> 17], 1);
            packed[pos] = make_int2(p.x & 0x1FFFF, p.y);
        }
    }
}

// ---------------------------------------------------------------------------
// Aggregate + ReLU (r12, unchanged): 16 nodes x 16 lanes/block; tile's edge
// records bulk-staged in LDS; 8 independent 16B gathers in flight per lane.
// ---------------------------------------------------------------------------
__global__ __launch_bounds__(256) void gcn_aggregate(const int* __restrict__ row_start,
                                                     const int2* __restrict__ packed,
                                                     const unsigned short* __restrict__ support,
                                                     float* __restrict__ out) {
    __shared__ int2 ep[kTileCap];
    const int n0 = blockIdx.x * 16;
    const int e0 = row_start[n0];
    const int eN = row_start[n0 + 16] - e0;
    const int nStage = min(eN, kTileCap);
    for (int i = threadIdx.x; i < nStage; i += 256)
        ep[i] = packed[e0 + i];
    __syncthreads();

    const int n  = n0 + (threadIdx.x >> 4);
    const int f8 = (threadIdx.x & 15) * 8;
    const unsigned short* sb = support + f8;
    const int s0 = row_start[n]     - e0;
    const int s1 = row_start[n + 1] - e0;

    float acc[8];
#pragma unroll
    for (int j = 0; j < 8; ++j) acc[j] = 0.f;

    if (eN <= kTileCap) {
        int i = s0;
        for (; i + 7 < s1; i += 8) {
            int2 p[8];
#pragma unroll
            for (int k = 0; k < 8; ++k) p[k] = ep[i + k];
            ush8 g[8];
#pragma unroll
            for (int k = 0; k < 8; ++k)
                g[k] = *reinterpret_cast<const ush8*>(sb + (size_t)p[k].x * kOutF);
#pragma unroll
            for (int k = 0; k < 8; ++k) {
                const float v = __int_as_float(p[k].y);
#pragma unroll
                for (int j = 0; j < 8; ++j) acc[j] += v * bf2f(g[k][j]);
            }
        }
        for (; i < s1; ++i) {
            const int2 p = ep[i];
            const float v = __int_as_float(p.y);
            const ush8 g = *reinterpret_cast<const ush8*>(sb + (size_t)p.x * kOutF);
#pragma unroll
            for (int j = 0; j < 8; ++j) acc[j] += v * bf2f(g[j]);
        }
    } else {
        int i = s0;
        for (; i + 3 < s1; i += 4) {
            const int2 p0 = packed[e0 + i];
            const int2 p1 = packed[e0 + i + 1];
            const int2 p2 = packed[e0 + i + 2];
            const int2 p3 = packed[e0 + i + 3];
            const ush8 a0 = *reinterpret_cast<const ush8*>(sb + (size_t)p0.x * kOutF);
            const ush8 a1 = *reinterpret_cast<const ush8*>(sb + (size_t)p1.x * kOutF);
            const ush8 a2 = *reinterpret_cast<const ush8*>(sb + (size_t)p2.x * kOutF);
            const ush8 a3 = *reinterpret_cast<const ush8*>(sb + (size_t)p3.x * kOutF);
            const float v0 = __int_as_float(p0.y), v1 = __int_as_float(p1.y);
            const float v2 = __int_as_float(p2.y), v3 = __int_as_float(p3.y);
#pragma unroll
            for (int j = 0; j < 8; ++j) {
                acc[j] += v0 * bf2f(a0[j]);
                acc[j] += v1 * bf2f(a1[j]);
                acc[j] += v2 * bf2f(a2[j]);
                acc[j] += v3 * bf2f(a3[j]);
            }
        }
        for (; i < s1; ++i) {
            const int2 p = packed[e0 + i];
            const float v = __int_as_float(p.y);
            const ush8 a = *reinterpret_cast<const ush8*>(sb + (size_t)p.x * kOutF);
#pragma unroll
            for (int j = 0; j < 8; ++j) acc[j] += v * bf2f(a[j]);
        }
    }

    float4 o0 = make_float4(fmaxf(acc[0], 0.f), fmaxf(acc[1], 0.f),
                            fmaxf(acc[2], 0.f), fmaxf(acc[3], 0.f));
    float4 o1 = make_float4(fmaxf(acc[4], 0.f), fmaxf(acc[5], 0.f),
                            fmaxf(acc[6], 0.f), fmaxf(acc[7], 0.f));
    *reinterpret_cast<float4*>(out + (size_t)n * kOutF + f8)     = o0;
    *reinterpret_cast<float4*>(out + (size_t)n * kOutF + f8 + 4) = o1;
}

extern "C" void kernel_launch(void* const* d_in, const int* in_sizes, int n_in,
                              void* d_out, int out_size, void* d_ws, size_t ws_size,
                              hipStream_t stream) {
    const float* x    = (const float*)d_in[0];
    const int*   erow = (const int*)  d_in[1];
    const int*   ecol = (const int*)  d_in[2];
    const float* eval = (const float*)d_in[3];
    const float* W    = (const float*)d_in[4];
    const float* b    = (const float*)d_in[5];
    float* out = (float*)d_out;

    char* ws = (char*)d_ws;
    unsigned short* support = (unsigned short*)(ws);       // 25,600,000 B (row-major [N][128])
    int2* packed      = (int2*)(ws + 25600000);            // 12,800,000 B
    int*  row_start   = (int*) (ws + 38400000);            //    400,004 B
    int*  bucket_tot  = (int*) (ws + 38800008);            //      4,096 B
    int*  bucket_base = (int*) (ws + 38804104);            //      4,100 B
    int*  cursor      = (int*) (ws + 38808204);            //      4,096 B

    hipMemsetAsync(bucket_tot, 0, kNB * sizeof(int), stream);

    // 1) support = bf16(x@W + b); each block also histograms its edge slice
    gcn_gemm<<<kGemmBlocks, 256, 0, stream>>>(x, W, b, support, erow, bucket_tot);

    // 2) CSR build: scan -> bin -> place
    gcn_bscan<<<1, 256, 0, stream>>>(bucket_tot, bucket_base, cursor, row_start);
    gcn_bin  <<<kBinBlocks, 256, 0, stream>>>(erow, ecol, eval, cursor, packed);
    gcn_place<<<kNB, 256, 0, stream>>>(bucket_base, row_start, packed);

    // 3) aggregate + relu
    gcn_aggregate<<<kTiles, 256, 0, stream>>>(row_start, packed, support, out);
}